// Round 1
// baseline (637.346 us; speedup 1.0000x reference)
//
#include <hip/hip_runtime.h>
#include <hip/hip_bf16.h>
#include <math.h>

#define BATCH 64
#define TT 512
#define HH 1024
#define KK 8
#define ROWS (BATCH * TT)          // 32768
#define SEG  (ROWS * KK)           // 262144 floats per logits output
#define TAGS_OFF (3 * SEG)         // 786432
#define LOSS_OFF (TAGS_OFF + BATCH * 3 * TT)  // 884736

// ---------------------------------------------------------------------------
// Kernel 1: fused 3-head GEMM  logits[m][row][c] = enc[row][:] @ W_m[:][c] + b_m[c]
// block = 256 threads (4 waves), each wave: 8 rows x 8 h-groups
// ---------------------------------------------------------------------------
#define FMA8(base, w0, w1, xe)                          \
    acc[base + 0] = fmaf(xe, w0.x, acc[base + 0]);      \
    acc[base + 1] = fmaf(xe, w0.y, acc[base + 1]);      \
    acc[base + 2] = fmaf(xe, w0.z, acc[base + 2]);      \
    acc[base + 3] = fmaf(xe, w0.w, acc[base + 3]);      \
    acc[base + 4] = fmaf(xe, w1.x, acc[base + 4]);      \
    acc[base + 5] = fmaf(xe, w1.y, acc[base + 5]);      \
    acc[base + 6] = fmaf(xe, w1.z, acc[base + 6]);      \
    acc[base + 7] = fmaf(xe, w1.w, acc[base + 7]);

__global__ __launch_bounds__(256) void gemm_heads(
    const float* __restrict__ enc,
    const float* __restrict__ Wt, const float* __restrict__ bt,
    const float* __restrict__ Wp, const float* __restrict__ bpv,
    const float* __restrict__ Wm, const float* __restrict__ bm,
    float* __restrict__ out)
{
    int tid  = threadIdx.x;
    int wave = tid >> 6;
    int lane = tid & 63;
    int r = lane >> 3;   // row within wave
    int g = lane & 7;    // h-group
    int row = blockIdx.x * 32 + wave * 8 + r;

    const float4* xrow = (const float4*)(enc + (size_t)row * HH);

    float acc[24];
#pragma unroll
    for (int c = 0; c < 24; ++c) acc[c] = 0.f;

#pragma unroll 2
    for (int j = 0; j < 32; ++j) {
        int f4 = g + 8 * j;          // float4 index within row, 0..255
        float4 x = xrow[f4];
        int h = 4 * f4;
        const float4* wt = (const float4*)(Wt + (size_t)h * 8);
        const float4* wp = (const float4*)(Wp + (size_t)h * 8);
        const float4* wm = (const float4*)(Wm + (size_t)h * 8);
#pragma unroll
        for (int e = 0; e < 4; ++e) {
            float xe = (e == 0) ? x.x : (e == 1) ? x.y : (e == 2) ? x.z : x.w;
            float4 t0 = wt[2 * e], t1 = wt[2 * e + 1];
            FMA8(0, t0, t1, xe);
            float4 p0 = wp[2 * e], p1 = wp[2 * e + 1];
            FMA8(8, p0, p1, xe);
            float4 m0 = wm[2 * e], m1 = wm[2 * e + 1];
            FMA8(16, m0, m1, xe);
        }
    }

    // reduce over the 8 h-groups (xor 1,2,4 stays within an r-group)
#pragma unroll
    for (int c = 0; c < 24; ++c) {
        acc[c] += __shfl_xor(acc[c], 1);
        acc[c] += __shfl_xor(acc[c], 2);
        acc[c] += __shfl_xor(acc[c], 4);
    }

    if (g == 0) {
        float* o0 = out + (size_t)row * 8;
        float* o1 = out + SEG + (size_t)row * 8;
        float* o2 = out + 2 * (size_t)SEG + (size_t)row * 8;
        float4 a = make_float4(acc[0] + bt[0], acc[1] + bt[1], acc[2] + bt[2], acc[3] + bt[3]);
        float4 b = make_float4(acc[4] + bt[4], acc[5] + bt[5], acc[6] + bt[6], acc[7] + bt[7]);
        ((float4*)o0)[0] = a; ((float4*)o0)[1] = b;
        a = make_float4(acc[8] + bpv[0], acc[9] + bpv[1], acc[10] + bpv[2], acc[11] + bpv[3]);
        b = make_float4(acc[12] + bpv[4], acc[13] + bpv[5], acc[14] + bpv[6], acc[15] + bpv[7]);
        ((float4*)o1)[0] = a; ((float4*)o1)[1] = b;
        a = make_float4(acc[16] + bm[0], acc[17] + bm[1], acc[18] + bm[2], acc[19] + bm[3]);
        b = make_float4(acc[20] + bm[4], acc[21] + bm[5], acc[22] + bm[6], acc[23] + bm[7]);
        ((float4*)o2)[0] = a; ((float4*)o2)[1] = b;
    }
}

// ---------------------------------------------------------------------------
// Kernel 2: fused Viterbi + CRF forward per (head, batch) sequence.
// 192 blocks x 64 threads. lane = kn*8 + kp  (kn = next state, kp = prev state)
// ---------------------------------------------------------------------------
__global__ __launch_bounds__(64) void crf_vit(
    const float* __restrict__ logits,   // [3][B][T][K] (= d_out base)
    const int* __restrict__ labels,     // [B][3T]
    const int* __restrict__ lens,       // [B]
    const float* __restrict__ trans_t,
    const float* __restrict__ trans_p,
    const float* __restrict__ trans_m,
    float* __restrict__ out_tags,       // [B][3T] as float  (d_out + TAGS_OFF)
    float* __restrict__ partial)        // [192] per-seq loss partials (ws)
{
    __shared__ float llds[TT * KK];            // 16 KB: this sequence's logits
    __shared__ unsigned char bp[TT][KK];       // 4 KB: backpointers (t = 1..511)

    int blk  = blockIdx.x;
    int h    = blk >> 6;     // 0..2 head
    int b    = blk & 63;     // batch
    int lane = threadIdx.x;
    int kn   = lane >> 3;
    int kp   = lane & 7;

    const float* L = logits + ((size_t)h * BATCH + b) * (TT * KK);

    // stage logits into LDS (coalesced float4)
    const float4* Lv = (const float4*)L;
    float4* lldsv = (float4*)llds;
#pragma unroll
    for (int i = 0; i < 16; ++i) lldsv[lane + 64 * i] = Lv[lane + 64 * i];
    __syncthreads();

    const float* TR = (h == 0) ? trans_t : (h == 1) ? trans_p : trans_m;
    float tr = TR[kp * KK + kn];    // trans[kp][kn], constant per lane
    int len = lens[b];
    int src = (kp << 3);            // lane to fetch alpha[kp] from after a step

    float av = llds[kp];            // viterbi alpha[kp]  (init = logits[:,0])
    float al = av;                  // logsumexp alpha[kp]

    for (int t = 1; t < TT; ++t) {
        float lt = llds[t * 8 + kn];

        // ---- Viterbi: argmax over kp (tie -> smallest kp, matches jnp.argmax)
        float v = av + tr;
        int  vi = kp;
#pragma unroll
        for (int d = 1; d <= 4; d <<= 1) {
            float ov = __shfl_xor(v, d);
            int   oi = __shfl_xor(vi, d);
            if (ov > v || (ov == v && oi < vi)) { v = ov; vi = oi; }
        }
        if (kp == 0) bp[t][kn] = (unsigned char)vi;
        float newv = v + lt;

        // ---- CRF: logsumexp over kp
        float s = al + tr;
        float m = s;
#pragma unroll
        for (int d = 1; d <= 4; d <<= 1) m = fmaxf(m, __shfl_xor(m, d));
        float e = __expf(s - m);
#pragma unroll
        for (int d = 1; d <= 4; d <<= 1) e += __shfl_xor(e, d);
        float newl = m + __logf(e) + lt;

        av = __shfl(newv, src);
        float nal = __shfl(newl, src);
        if (t < len) al = nal;      // wave-uniform mask: alpha freezes at t >= len
    }

    // ---- last = argmax over states of final viterbi alpha
    float fv = av; int fi = kp;     // duplicates across kn share the same idx
#pragma unroll
    for (int d = 1; d <= 32; d <<= 1) {
        float ov = __shfl_xor(fv, d);
        int   oi = __shfl_xor(fi, d);
        if (ov > fv || (ov == fv && oi < fi)) { fv = ov; fi = oi; }
    }
    int last = fi;

    // ---- logZ = LSE over the 8 distinct CRF alphas (lanes 0..7 hold kp=0..7)
    float zv = (lane < 8) ? al : -INFINITY;
    float zm = zv;
#pragma unroll
    for (int d = 1; d <= 32; d <<= 1) zm = fmaxf(zm, __shfl_xor(zm, d));
    float ze = (lane < 8) ? __expf(zv - zm) : 0.f;
#pragma unroll
    for (int d = 1; d <= 32; d <<= 1) ze += __shfl_xor(ze, d);
    float logZ = zm + __logf(ze);

    // ---- emit + transition scores (lane-parallel over t)
    const int* lab = labels + b * (3 * TT) + h * TT;
    int off = h * 8;
    float sc = 0.f;
#pragma unroll
    for (int j = 0; j < 8; ++j) {
        int t = lane + 64 * j;
        if (t < len) {
            int tg = lab[t] - off;
            sc += llds[t * 8 + tg];
            if (t >= 1) {
                int tp = lab[t - 1] - off;
                sc += TR[tp * 8 + tg];
            }
        }
    }
#pragma unroll
    for (int d = 1; d <= 32; d <<= 1) sc += __shfl_xor(sc, d);

    if (lane == 0) partial[blk] = logZ - sc;   // -(emit + trans - logZ)

    __syncthreads();  // bp fully written before lane-0 backtrack

    // ---- backtrack (serial, lane 0)
    if (lane == 0) {
        float* otag = out_tags + b * (3 * TT) + h * TT;
        int cur = last;
        otag[TT - 1] = (float)(cur + off);
        for (int t = TT - 1; t >= 1; --t) {
            cur = bp[t][cur];
            otag[t - 1] = (float)(cur + off);
        }
    }
}

// ---------------------------------------------------------------------------
// Kernel 3: deterministic loss reduction (192 partials -> scalar)
// ---------------------------------------------------------------------------
__global__ __launch_bounds__(64) void loss_reduce(
    const float* __restrict__ partial, float* __restrict__ out_loss)
{
    int lane = threadIdx.x;
    float s = partial[lane] + partial[lane + 64] + partial[lane + 128];
#pragma unroll
    for (int d = 1; d <= 32; d <<= 1) s += __shfl_xor(s, d);
    if (lane == 0) *out_loss = s;
}

// ---------------------------------------------------------------------------
extern "C" void kernel_launch(void* const* d_in, const int* in_sizes, int n_in,
                              void* d_out, int out_size, void* d_ws, size_t ws_size,
                              hipStream_t stream) {
    const float* enc   = (const float*)d_in[0];
    const int*   labels= (const int*)d_in[1];
    const int*   lens  = (const int*)d_in[2];
    const float* Wt    = (const float*)d_in[3];
    const float* bt    = (const float*)d_in[4];
    const float* Wp    = (const float*)d_in[5];
    const float* bpv   = (const float*)d_in[6];
    const float* Wm    = (const float*)d_in[7];
    const float* bm    = (const float*)d_in[8];
    const float* tr_t  = (const float*)d_in[9];
    const float* tr_p  = (const float*)d_in[10];
    const float* tr_m  = (const float*)d_in[11];

    float* out = (float*)d_out;
    float* partial = (float*)d_ws;   // 192 floats

    gemm_heads<<<ROWS / 32, 256, 0, stream>>>(enc, Wt, bt, Wp, bpv, Wm, bm, out);
    crf_vit<<<192, 64, 0, stream>>>(out, labels, lens, tr_t, tr_p, tr_m,
                                    out + TAGS_OFF, partial);
    loss_reduce<<<1, 64, 0, stream>>>(partial, out + LOSS_OFF);
}

// Round 2
// 528.043 us; speedup vs baseline: 1.2070x; 1.2070x over previous
//
#include <hip/hip_runtime.h>
#include <hip/hip_bf16.h>
#include <math.h>

#define BATCH 64
#define TT 512
#define HH 1024
#define KK 8
#define ROWS (BATCH * TT)          // 32768
#define SEG  (ROWS * KK)           // 262144 floats per logits output
#define TAGS_OFF (3 * SEG)         // 786432
#define LOSS_OFF (TAGS_OFF + BATCH * 3 * TT)  // 884736

// ---------------------------------------------------------------------------
// Kernel 1: fused 3-head GEMM. block = 128 threads (2 waves), 64 rows/block.
// lane = row; wave w owns h in [512w, 512w+512) -> weight index is wave-uniform
// (readfirstlane) so W reads become s_loads; x staged in LDS (pad 33, 2-way free).
// Double-buffered; global loads issued before compute (latency hidden).
// ---------------------------------------------------------------------------
__global__ __launch_bounds__(128) void gemm_heads(
    const float* __restrict__ enc,
    const float* __restrict__ Wt, const float* __restrict__ bt,
    const float* __restrict__ Wp, const float* __restrict__ bpv,
    const float* __restrict__ Wm, const float* __restrict__ bm,
    float* __restrict__ out)
{
    __shared__ float xt[2][2][64][33];   // [buf][half][row][col]  67.6 KB
    __shared__ float red[64][25];        // cross-wave reduce       6.4 KB

    int tid  = threadIdx.x;
    int lane = tid & 63;
    int wv   = __builtin_amdgcn_readfirstlane(tid >> 6);  // 0 or 1, SGPR
    int rowbase = blockIdx.x * 64;
    const float* encb = enc + (size_t)rowbase * HH;

    float acc[24];
#pragma unroll
    for (int c = 0; c < 24; ++c) acc[c] = 0.f;

    float4 regs[8];

#define STAGE_LOAD(it)                                                        \
    {                                                                         \
        _Pragma("unroll")                                                     \
        for (int hf = 0; hf < 2; ++hf) {                                      \
            _Pragma("unroll")                                                 \
            for (int i = 0; i < 4; ++i) {                                     \
                int idx = tid + 128 * i;                                      \
                int r = idx >> 3, cq = idx & 7;                               \
                regs[hf * 4 + i] = *(const float4*)(encb + (size_t)r * HH +   \
                                     hf * 512 + (it) * 32 + 4 * cq);          \
            }                                                                 \
        }                                                                     \
    }
#define STAGE_WRITE(buf)                                                      \
    {                                                                         \
        _Pragma("unroll")                                                     \
        for (int hf = 0; hf < 2; ++hf) {                                      \
            _Pragma("unroll")                                                 \
            for (int i = 0; i < 4; ++i) {                                     \
                int idx = tid + 128 * i;                                      \
                int r = idx >> 3, cq = idx & 7;                               \
                float4 v = regs[hf * 4 + i];                                  \
                float* p = &xt[buf][hf][r][4 * cq];                           \
                p[0] = v.x; p[1] = v.y; p[2] = v.z; p[3] = v.w;               \
            }                                                                 \
        }                                                                     \
    }

    STAGE_LOAD(0);
    STAGE_WRITE(0);

    for (int it = 0; it < 16; ++it) {
        __syncthreads();
        int cb = it & 1, nb = (it + 1) & 1;
        if (it < 15) STAGE_LOAD(it + 1);      // issue next-tile loads early

        int hbase = wv * 512 + it * 32;       // SGPR
#pragma unroll
        for (int cq = 0; cq < 8; ++cq) {
            const float* xp = &xt[cb][wv][lane][4 * cq];
            float x0 = xp[0], x1 = xp[1], x2 = xp[2], x3 = xp[3];
            const float* wt = Wt + (size_t)(hbase + 4 * cq) * 8;   // uniform -> s_load
            const float* wp = Wp + (size_t)(hbase + 4 * cq) * 8;
            const float* wm = Wm + (size_t)(hbase + 4 * cq) * 8;
#pragma unroll
            for (int e = 0; e < 4; ++e) {
                float xe = e == 0 ? x0 : e == 1 ? x1 : e == 2 ? x2 : x3;
#pragma unroll
                for (int o = 0; o < 8; ++o) {
                    acc[o]      = fmaf(xe, wt[e * 8 + o], acc[o]);
                    acc[8 + o]  = fmaf(xe, wp[e * 8 + o], acc[8 + o]);
                    acc[16 + o] = fmaf(xe, wm[e * 8 + o], acc[16 + o]);
                }
            }
        }
        if (it < 15) STAGE_WRITE(nb);         // write-late after compute
    }

    if (wv == 1) {
#pragma unroll
        for (int c = 0; c < 24; ++c) red[lane][c] = acc[c];
    }
    __syncthreads();
    if (wv == 0) {
        size_t row = rowbase + lane;
        float* o0 = out + row * 8;
        float* o1 = out + SEG + row * 8;
        float* o2 = out + 2 * (size_t)SEG + row * 8;
        float s[24];
#pragma unroll
        for (int c = 0; c < 24; ++c) s[c] = acc[c] + red[lane][c];
        ((float4*)o0)[0] = make_float4(s[0] + bt[0],  s[1] + bt[1],  s[2] + bt[2],  s[3] + bt[3]);
        ((float4*)o0)[1] = make_float4(s[4] + bt[4],  s[5] + bt[5],  s[6] + bt[6],  s[7] + bt[7]);
        ((float4*)o1)[0] = make_float4(s[8] + bpv[0], s[9] + bpv[1], s[10] + bpv[2], s[11] + bpv[3]);
        ((float4*)o1)[1] = make_float4(s[12] + bpv[4], s[13] + bpv[5], s[14] + bpv[6], s[15] + bpv[7]);
        ((float4*)o2)[0] = make_float4(s[16] + bm[0], s[17] + bm[1], s[18] + bm[2], s[19] + bm[3]);
        ((float4*)o2)[1] = make_float4(s[20] + bm[4], s[21] + bm[5], s[22] + bm[6], s[23] + bm[7]);
    }
#undef STAGE_LOAD
#undef STAGE_WRITE
}

// ---------------------------------------------------------------------------
// Kernel 2: fused Viterbi + CRF forward, 192 blocks x 64 threads (1 wave/seq).
// Alternating-field layout: even step kp=lo reduce xor{1,2,4}; odd step kp=hi
// reduce xor{8,16,32} -> no per-step broadcast shuffle. LSE uses a 4-deep
// stale-max pipeline (valid for any m; drift <= ~7/step << exp range).
// Backtrack: per-lane 8-step map composition + lane-0 chunk walk + expand.
// ---------------------------------------------------------------------------
__global__ __launch_bounds__(64) void crf_vit(
    const float* __restrict__ logits,
    const int* __restrict__ labels,
    const int* __restrict__ lens,
    const float* __restrict__ trans_t,
    const float* __restrict__ trans_p,
    const float* __restrict__ trans_m,
    float* __restrict__ out_tags,
    float* __restrict__ partial)
{
    __shared__ float llds[TT * KK];        // 16 KB logits for this sequence
    __shared__ unsigned bpw[TT * 2];       // 4 KB backpointers (rows of 8 bytes)
    __shared__ unsigned fmapw[64][2];      // chunk maps
    __shared__ unsigned char bnd[64];      // boundary states cur_{8l}

    int blk = blockIdx.x;
    int h   = blk >> 6;
    int b   = blk & 63;
    int lane = threadIdx.x;
    int hi = lane >> 3, lo = lane & 7;

    const float* L = logits + ((size_t)h * BATCH + b) * (TT * KK);
    const float4* Lv = (const float4*)L;
    float4* lv = (float4*)llds;
#pragma unroll
    for (int i = 0; i < 16; ++i) lv[lane + 64 * i] = Lv[lane + 64 * i];
    __syncthreads();

    const float* TR = (h == 0) ? trans_t : (h == 1) ? trans_p : trans_m;
    float trA = TR[lo * 8 + hi];   // even-type: kp=lo, kn=hi
    float trB = TR[hi * 8 + lo];   // odd-type:  kp=hi, kn=lo
    int len = lens[b];

    float av = llds[lo];           // viterbi alpha, indexed by lo
    float al = av;                 // lse alpha

    // stale-max pipeline init (exact max of alpha_0)
    float m = al;
#pragma unroll
    for (int d = 1; d <= 32; d <<= 1) m = fmaxf(m, __shfl_xor(m, d));
    float m_use = m, m1 = m, m2 = m, m3 = m;

#define CRF_STEP(t, TRX, KN, MYIDX, X1, X2, X4)                                \
    {                                                                          \
        float lt = llds[(t) * 8 + (KN)];                                       \
        /* Viterbi: exact max, min-index tiebreak */                           \
        float v = av + (TRX); int vi = (MYIDX);                                \
        { float ov; int oi;                                                    \
          ov = __shfl_xor(v, X1); oi = __shfl_xor(vi, X1);                     \
          if (ov > v || (ov == v && oi < vi)) { v = ov; vi = oi; }             \
          ov = __shfl_xor(v, X2); oi = __shfl_xor(vi, X2);                     \
          if (ov > v || (ov == v && oi < vi)) { v = ov; vi = oi; }             \
          ov = __shfl_xor(v, X4); oi = __shfl_xor(vi, X4);                     \
          if (ov > v || (ov == v && oi < vi)) { v = ov; vi = oi; } }           \
        if ((MYIDX) == 0) ((unsigned char*)bpw)[(t) * 8 + (KN)] = (unsigned char)vi; \
        av = v + lt;                                                           \
        /* LSE with stale max (any m valid; pipeline keeps it off chain) */    \
        float e = __expf(al + (TRX) - m_use);                                  \
        e += __shfl_xor(e, X1); e += __shfl_xor(e, X2); e += __shfl_xor(e, X4);\
        float nal = m_use + __logf(e) + lt;                                    \
        if ((t) < len) al = nal;                                               \
        float mr = al;                                                         \
        mr = fmaxf(mr, __shfl_xor(mr, 1));  mr = fmaxf(mr, __shfl_xor(mr, 2)); \
        mr = fmaxf(mr, __shfl_xor(mr, 4));  mr = fmaxf(mr, __shfl_xor(mr, 8)); \
        mr = fmaxf(mr, __shfl_xor(mr, 16)); mr = fmaxf(mr, __shfl_xor(mr, 32));\
        m_use = m1; m1 = m2; m2 = m3; m3 = mr;                                 \
    }

    for (int t = 1; t <= 509; t += 2) {
        CRF_STEP(t,     trA, hi, lo, 1, 2, 4);
        CRF_STEP(t + 1, trB, lo, hi, 8, 16, 32);
    }
    CRF_STEP(511, trA, hi, lo, 1, 2, 4);
#undef CRF_STEP

    // ---- last = argmax of final viterbi alpha (indexed by hi, replicated x8)
    float fv = av; int fi = hi;
#pragma unroll
    for (int d = 1; d <= 32; d <<= 1) {
        float ov = __shfl_xor(fv, d);
        int   oi = __shfl_xor(fi, d);
        if (ov > fv || (ov == fv && oi < fi)) { fv = ov; fi = oi; }
    }
    int last = fi;

    // ---- logZ: al replicated x8 -> LSE over 64 lanes minus ln(8)
    float zm = al;
#pragma unroll
    for (int d = 1; d <= 32; d <<= 1) zm = fmaxf(zm, __shfl_xor(zm, d));
    float ze = __expf(al - zm);
#pragma unroll
    for (int d = 1; d <= 32; d <<= 1) ze += __shfl_xor(ze, d);
    float logZ = zm + __logf(ze) - 2.0794415416798357f;

    // ---- emit + transition scores (lane-parallel over t)
    const int* lab = labels + b * (3 * TT) + h * TT;
    int off = h * 8;
    float sc = 0.f;
#pragma unroll
    for (int j = 0; j < 8; ++j) {
        int t = lane + 64 * j;
        if (t < len) {
            int tg = lab[t] - off;
            sc += llds[t * 8 + tg];
            if (t >= 1) {
                int tp = lab[t - 1] - off;
                sc += TR[tp * 8 + tg];
            }
        }
    }
#pragma unroll
    for (int d = 1; d <= 32; d <<= 1) sc += __shfl_xor(sc, d);

    if (lane == 0) partial[blk] = logZ - sc;

    __syncthreads();  // bp writes visible

    // ---- Phase A: lane l composes bp maps for t in [8l+1, 8l+8] (identity pad at t=512)
    int t0 = lane * 8;
    unsigned rw[16];
#pragma unroll
    for (int j = 0; j < 8; ++j) {
        int t = t0 + 1 + j;
        if (t <= 511) { rw[2 * j] = bpw[t * 2]; rw[2 * j + 1] = bpw[t * 2 + 1]; }
        else          { rw[2 * j] = 0x03020100u; rw[2 * j + 1] = 0x07060504u; }
    }
    unsigned sv[8];
#pragma unroll
    for (int i = 0; i < 8; ++i) sv[i] = i;
#pragma unroll
    for (int j = 7; j >= 0; --j) {
        unsigned d0 = rw[2 * j], d1 = rw[2 * j + 1];
#pragma unroll
        for (int i = 0; i < 8; ++i) {
            unsigned s = sv[i];
            unsigned d = (s < 4) ? d0 : d1;
            sv[i] = (d >> (8 * (s & 3))) & 0xffu;
        }
    }
    fmapw[lane][0] = sv[0] | (sv[1] << 8) | (sv[2] << 16) | (sv[3] << 24);
    fmapw[lane][1] = sv[4] | (sv[5] << 8) | (sv[6] << 16) | (sv[7] << 24);
    __syncthreads();

    // ---- Phase B: lane 0 walks 64 chunk maps
    if (lane == 0) {
        unsigned cur = (unsigned)last;
        for (int l = 63; l >= 0; --l) {
            unsigned d = (cur < 4) ? fmapw[l][0] : fmapw[l][1];
            cur = (d >> (8 * (cur & 3))) & 0xffu;
            bnd[l] = (unsigned char)cur;
        }
    }
    __syncthreads();

    // ---- Phase C: expand within chunk, write tags
    float* otag = out_tags + b * (3 * TT) + h * TT;
    unsigned curr = (lane == 63) ? (unsigned)last : (unsigned)bnd[lane + 1];
#pragma unroll
    for (int j = 7; j >= 0; --j) {
        unsigned d = (curr < 4) ? rw[2 * j] : rw[2 * j + 1];
        curr = (d >> (8 * (curr & 3))) & 0xffu;   // cur_{t-1}, t = t0+1+j
        otag[t0 + j] = (float)((int)curr + off);
    }
}

// ---------------------------------------------------------------------------
// Kernel 3: deterministic loss reduction (192 partials -> scalar)
// ---------------------------------------------------------------------------
__global__ __launch_bounds__(64) void loss_reduce(
    const float* __restrict__ partial, float* __restrict__ out_loss)
{
    int lane = threadIdx.x;
    float s = partial[lane] + partial[lane + 64] + partial[lane + 128];
#pragma unroll
    for (int d = 1; d <= 32; d <<= 1) s += __shfl_xor(s, d);
    if (lane == 0) *out_loss = s;
}

// ---------------------------------------------------------------------------
extern "C" void kernel_launch(void* const* d_in, const int* in_sizes, int n_in,
                              void* d_out, int out_size, void* d_ws, size_t ws_size,
                              hipStream_t stream) {
    const float* enc    = (const float*)d_in[0];
    const int*   labels = (const int*)d_in[1];
    const int*   lens   = (const int*)d_in[2];
    const float* Wt     = (const float*)d_in[3];
    const float* bt     = (const float*)d_in[4];
    const float* Wp     = (const float*)d_in[5];
    const float* bpv    = (const float*)d_in[6];
    const float* Wm     = (const float*)d_in[7];
    const float* bm     = (const float*)d_in[8];
    const float* tr_t   = (const float*)d_in[9];
    const float* tr_p   = (const float*)d_in[10];
    const float* tr_m   = (const float*)d_in[11];

    float* out = (float*)d_out;
    float* partial = (float*)d_ws;   // 192 floats

    gemm_heads<<<ROWS / 64, 128, 0, stream>>>(enc, Wt, bt, Wp, bpv, Wm, bm, out);
    crf_vit<<<192, 64, 0, stream>>>(out, labels, lens, tr_t, tr_p, tr_m,
                                    out + TAGS_OFF, partial);
    loss_reduce<<<1, 64, 0, stream>>>(partial, out + LOSS_OFF);
}

// Round 3
// 163.943 us; speedup vs baseline: 3.8876x; 3.2209x over previous
//
#include <hip/hip_runtime.h>
#include <hip/hip_bf16.h>
#include <math.h>

#define BATCH 64
#define TT 512
#define HH 1024
#define KK 8
#define ROWS (BATCH * TT)          // 32768
#define SEG  (ROWS * KK)           // 262144 floats per logits output
#define TAGS_OFF (3 * SEG)         // 786432
#define LOSS_OFF (TAGS_OFF + BATCH * 3 * TT)  // 884736

#define FMA8(base, w0, w1, xe)                          \
    acc[base + 0] = fmaf(xe, w0.x, acc[base + 0]);      \
    acc[base + 1] = fmaf(xe, w0.y, acc[base + 1]);      \
    acc[base + 2] = fmaf(xe, w0.z, acc[base + 2]);      \
    acc[base + 3] = fmaf(xe, w0.w, acc[base + 3]);      \
    acc[base + 4] = fmaf(xe, w1.x, acc[base + 4]);      \
    acc[base + 5] = fmaf(xe, w1.y, acc[base + 5]);      \
    acc[base + 6] = fmaf(xe, w1.z, acc[base + 6]);      \
    acc[base + 7] = fmaf(xe, w1.w, acc[base + 7]);

// ---------------------------------------------------------------------------
// Kernel 1: fused 3-head GEMM. 512 blocks x 256 thr (4 waves). Block owns 64
// rows; wave w owns h-quarter [256w,256w+256). Per-wave private double-buffered
// pipeline (no barriers in main loop): enc staged coalesced -> LDS transposed
// [h][row] (conflict-free reads); weights via uniform vector loads (L1/L2).
// In-block K-reduce via LDS at the end.
// ---------------------------------------------------------------------------
__global__ __launch_bounds__(256, 2) void gemm_heads(
    const float* __restrict__ enc,
    const float* __restrict__ Wt, const float* __restrict__ bt,
    const float* __restrict__ Wp, const float* __restrict__ bpv,
    const float* __restrict__ Wm, const float* __restrict__ bm,
    float* __restrict__ out)
{
    __shared__ float xl[4][2][16][65];   // 33.3 KB: per-wave double-buffered tiles
    __shared__ float red[3][64][25];     // 19.2 KB: cross-wave K-reduce

    int tid  = threadIdx.x;
    int lane = tid & 63;
    int wv   = __builtin_amdgcn_readfirstlane(tid >> 6);
    int rowbase = blockIdx.x * 64;
    const float* encb = enc + (size_t)rowbase * HH + wv * 256;

    int srow = lane >> 2;        // staging row (16 per j-iter)
    int sslot = lane & 3;        // staging float4 slot (4*4B*4 = 16 h per tile)

    float acc[24];
#pragma unroll
    for (int c = 0; c < 24; ++c) acc[c] = 0.f;

    float4 sreg[4];

#define LOADT(it)                                                             \
    {                                                                         \
        _Pragma("unroll")                                                     \
        for (int j = 0; j < 4; ++j)                                           \
            sreg[j] = *(const float4*)(encb + (size_t)(srow + 16 * j) * HH +  \
                                       (it) * 16 + sslot * 4);                \
    }
#define WRITET(buf)                                                           \
    {                                                                         \
        _Pragma("unroll")                                                     \
        for (int j = 0; j < 4; ++j) {                                         \
            xl[wv][buf][sslot * 4 + 0][srow + 16 * j] = sreg[j].x;            \
            xl[wv][buf][sslot * 4 + 1][srow + 16 * j] = sreg[j].y;            \
            xl[wv][buf][sslot * 4 + 2][srow + 16 * j] = sreg[j].z;            \
            xl[wv][buf][sslot * 4 + 3][srow + 16 * j] = sreg[j].w;            \
        }                                                                     \
    }

    LOADT(0);
    WRITET(0);

    for (int it = 0; it < 16; ++it) {
        int cb = it & 1;
        if (it < 15) LOADT(it + 1);          // issue next tile's global loads early

        const float* Wqt = Wt + (size_t)(wv * 256 + it * 16) * 8;
        const float* Wqp = Wp + (size_t)(wv * 256 + it * 16) * 8;
        const float* Wqm = Wm + (size_t)(wv * 256 + it * 16) * 8;

#pragma unroll 4
        for (int h = 0; h < 16; ++h) {
            float4 t0 = ((const float4*)(Wqt + h * 8))[0];
            float4 t1 = ((const float4*)(Wqt + h * 8))[1];
            float4 p0 = ((const float4*)(Wqp + h * 8))[0];
            float4 p1 = ((const float4*)(Wqp + h * 8))[1];
            float4 m0 = ((const float4*)(Wqm + h * 8))[0];
            float4 m1 = ((const float4*)(Wqm + h * 8))[1];
            float x = xl[wv][cb][h][lane];
            FMA8(0, t0, t1, x);
            FMA8(8, p0, p1, x);
            FMA8(16, m0, m1, x);
        }
        if (it < 15) WRITET(cb ^ 1);         // write-late (T14), same wave -> no barrier
    }
#undef LOADT
#undef WRITET

    if (wv != 0) {
#pragma unroll
        for (int c = 0; c < 24; ++c) red[wv - 1][lane][c] = acc[c];
    }
    __syncthreads();
    if (wv == 0) {
        float s[24];
#pragma unroll
        for (int c = 0; c < 24; ++c)
            s[c] = acc[c] + red[0][lane][c] + red[1][lane][c] + red[2][lane][c];
        size_t row = rowbase + lane;
        float* o0 = out + row * 8;
        float* o1 = out + SEG + row * 8;
        float* o2 = out + 2 * (size_t)SEG + row * 8;
        ((float4*)o0)[0] = make_float4(s[0] + bt[0],  s[1] + bt[1],  s[2] + bt[2],  s[3] + bt[3]);
        ((float4*)o0)[1] = make_float4(s[4] + bt[4],  s[5] + bt[5],  s[6] + bt[6],  s[7] + bt[7]);
        ((float4*)o1)[0] = make_float4(s[8] + bpv[0], s[9] + bpv[1], s[10] + bpv[2], s[11] + bpv[3]);
        ((float4*)o1)[1] = make_float4(s[12] + bpv[4], s[13] + bpv[5], s[14] + bpv[6], s[15] + bpv[7]);
        ((float4*)o2)[0] = make_float4(s[16] + bm[0], s[17] + bm[1], s[18] + bm[2], s[19] + bm[3]);
        ((float4*)o2)[1] = make_float4(s[20] + bm[4], s[21] + bm[5], s[22] + bm[6], s[23] + bm[7]);
    }
}

// ---------------------------------------------------------------------------
// Kernel 2: fused Viterbi + CRF. 192 blocks x 64 threads (1 wave/seq).
// Alternating-field recurrence; DPP for xor1/xor2/xor8, swizzle xor4/xor16,
// bpermute xor32; ballot-based argmax (no index shuffles); SGPR stale-max
// (readfirstlane, 4-deep) -- zero shuffles for max maintenance.
// ---------------------------------------------------------------------------
#define DPPF(x, ctrl) __int_as_float(__builtin_amdgcn_update_dpp(              \
    0, __float_as_int(x), ctrl, 0xF, 0xF, true))
#define SWIZF(x, pat) __int_as_float(__builtin_amdgcn_ds_swizzle(              \
    __float_as_int(x), pat))
#define BPERMF(a, x)  __int_as_float(__builtin_amdgcn_ds_bpermute(             \
    a, __float_as_int(x)))
// xor1 = quad_perm[1,0,3,2] = 0xB1 ; xor2 = quad_perm[2,3,0,1] = 0x4E
// xor8 = row_ror:8 = 0x128 ; xor4 = swizzle 0x101F ; xor16 = swizzle 0x401F

__global__ __launch_bounds__(64) void crf_vit(
    const float* __restrict__ logits,
    const int* __restrict__ labels,
    const int* __restrict__ lens,
    const float* __restrict__ trans_t,
    const float* __restrict__ trans_p,
    const float* __restrict__ trans_m,
    float* __restrict__ out_tags,
    float* __restrict__ partial)
{
    __shared__ float llds[TT * KK];        // 16 KB
    __shared__ unsigned bpw[TT * 2];       // 4 KB backpointers
    __shared__ unsigned fmapw[64][2];
    __shared__ unsigned char bnd[64];

    int blk = blockIdx.x;
    int h   = blk >> 6;
    int b   = blk & 63;
    int lane = threadIdx.x;
    int hi = lane >> 3, lo = lane & 7;
    int a32 = ((lane ^ 32) << 2);
    unsigned char* bpb = (unsigned char*)bpw;

    const float* L = logits + ((size_t)h * BATCH + b) * (TT * KK);
    const float4* Lv = (const float4*)L;
    float4* lv = (float4*)llds;
#pragma unroll
    for (int i = 0; i < 16; ++i) lv[lane + 64 * i] = Lv[lane + 64 * i];
    __syncthreads();

    const float* TR = (h == 0) ? trans_t : (h == 1) ? trans_p : trans_m;
    float trA = TR[lo * 8 + hi];   // even step: kp=lo, kn=hi
    float trB = TR[hi * 8 + lo];   // odd step:  kp=hi, kn=lo
    int len = lens[b];

    float av = llds[lo];
    float al = av;

    float m0 = __int_as_float(__builtin_amdgcn_readfirstlane(__float_as_int(al)));
    float m_use = m0, m1 = m0, m2 = m0, m3 = m0;

#define VSTEP_EVEN(t, LT)                                                      \
    {                                                                          \
        float v0 = av + trA;                                                   \
        float ra = fmaxf(v0, DPPF(v0, 0xB1));                                  \
        float rb = fmaxf(ra, DPPF(ra, 0x4E));                                  \
        float vmax = fmaxf(rb, SWIZF(rb, 0x101F));                             \
        unsigned long long mk = __ballot(v0 == vmax);                          \
        int vi = __builtin_ctz(((unsigned)(mk >> (lane & 56))) & 0xffu);       \
        if (lo == 0) bpb[(t) * 8 + hi] = (unsigned char)vi;                    \
        av = vmax + (LT);                                                      \
        float e0 = __expf(al + trA - m_use);                                   \
        float sa = e0 + DPPF(e0, 0xB1);                                        \
        float sb = sa + DPPF(sa, 0x4E);                                        \
        float es = sb + SWIZF(sb, 0x101F);                                     \
        float nal = m_use + __logf(es) + (LT);                                 \
        if ((t) < len) al = nal;                                               \
        m_use = m1; m1 = m2; m2 = m3;                                          \
        m3 = __int_as_float(__builtin_amdgcn_readfirstlane(__float_as_int(al)));\
    }
#define VSTEP_ODD(t, LT)                                                       \
    {                                                                          \
        float v0 = av + trB;                                                   \
        float ra = fmaxf(v0, DPPF(v0, 0x128));                                 \
        float rb = fmaxf(ra, SWIZF(ra, 0x401F));                               \
        float vmax = fmaxf(rb, BPERMF(a32, rb));                               \
        unsigned long long mk = __ballot(v0 == vmax);                          \
        unsigned long long sel = (mk >> lo) & 0x0101010101010101ULL;           \
        int vi = __builtin_ctzll(sel) >> 3;                                    \
        if (hi == 0) bpb[(t) * 8 + lo] = (unsigned char)vi;                    \
        av = vmax + (LT);                                                      \
        float e0 = __expf(al + trB - m_use);                                   \
        float sa = e0 + DPPF(e0, 0x128);                                       \
        float sb = sa + SWIZF(sa, 0x401F);                                     \
        float es = sb + BPERMF(a32, sb);                                       \
        float nal = m_use + __logf(es) + (LT);                                 \
        if ((t) < len) al = nal;                                               \
        m_use = m1; m1 = m2; m2 = m3;                                          \
        m3 = __int_as_float(__builtin_amdgcn_readfirstlane(__float_as_int(al)));\
    }

    float ltA = llds[8 + hi];
    float ltB = llds[16 + lo];
    for (int t = 1; t <= 509; t += 2) {
        float ltA2 = llds[(t + 2) * 8 + hi];            // prefetch (DS in-order)
        int tb = (t + 3 <= 511) ? (t + 3) : 511;
        float ltB2 = llds[tb * 8 + lo];
        VSTEP_EVEN(t, ltA);
        VSTEP_ODD(t + 1, ltB);
        ltA = ltA2; ltB = ltB2;
    }
    VSTEP_EVEN(511, ltA);
#undef VSTEP_EVEN
#undef VSTEP_ODD

    // ---- last = argmax of final viterbi alpha (indexed by hi, replicated over lo)
    {
        float ra = fmaxf(av, DPPF(av, 0x128));
        float rb = fmaxf(ra, SWIZF(ra, 0x401F));
        float vmax = fmaxf(rb, BPERMF(a32, rb));
        unsigned long long mk = __ballot(av == vmax);
        int last_ = __builtin_ctzll(mk) >> 3;
        // ---- logZ: reduce over hi-field only (true 8-state LSE)
        float zm = vmax;  // reuse? no: need max of al not av
        (void)zm;
        float za = fmaxf(al, DPPF(al, 0x128));
        float zb = fmaxf(za, SWIZF(za, 0x401F));
        float zmax = fmaxf(zb, BPERMF(a32, zb));
        float ze0 = __expf(al - zmax);
        float zs = ze0 + DPPF(ze0, 0x128);
        float zs2 = zs + SWIZF(zs, 0x401F);
        float zsum = zs2 + BPERMF(a32, zs2);
        float logZ = zmax + __logf(zsum);

        // ---- emit + transition scores (lane-parallel over t)
        const int* lab = labels + b * (3 * TT) + h * TT;
        int off = h * 8;
        float sc = 0.f;
#pragma unroll
        for (int j = 0; j < 8; ++j) {
            int t = lane + 64 * j;
            if (t < len) {
                int tg = lab[t] - off;
                sc += llds[t * 8 + tg];
                if (t >= 1) {
                    int tp = lab[t - 1] - off;
                    sc += TR[tp * 8 + tg];
                }
            }
        }
#pragma unroll
        for (int d = 1; d <= 32; d <<= 1) sc += __shfl_xor(sc, d);

        if (lane == 0) partial[blk] = logZ - sc;

        __syncthreads();  // bp writes visible

        // ---- Phase A: lane l composes bp maps for t in [8l+1, 8l+8]
        int t0 = lane * 8;
        unsigned rw[16];
#pragma unroll
        for (int j = 0; j < 8; ++j) {
            int t = t0 + 1 + j;
            if (t <= 511) { rw[2 * j] = bpw[t * 2]; rw[2 * j + 1] = bpw[t * 2 + 1]; }
            else          { rw[2 * j] = 0x03020100u; rw[2 * j + 1] = 0x07060504u; }
        }
        unsigned sv[8];
#pragma unroll
        for (int i = 0; i < 8; ++i) sv[i] = i;
#pragma unroll
        for (int j = 7; j >= 0; --j) {
            unsigned d0 = rw[2 * j], d1 = rw[2 * j + 1];
#pragma unroll
            for (int i = 0; i < 8; ++i) {
                unsigned s = sv[i];
                unsigned d = (s < 4) ? d0 : d1;
                sv[i] = (d >> (8 * (s & 3))) & 0xffu;
            }
        }
        fmapw[lane][0] = sv[0] | (sv[1] << 8) | (sv[2] << 16) | (sv[3] << 24);
        fmapw[lane][1] = sv[4] | (sv[5] << 8) | (sv[6] << 16) | (sv[7] << 24);
        __syncthreads();

        // ---- Phase B: lane 0 walks 64 chunk maps
        if (lane == 0) {
            unsigned cur = (unsigned)last_;
            for (int l = 63; l >= 0; --l) {
                unsigned d = (cur < 4) ? fmapw[l][0] : fmapw[l][1];
                cur = (d >> (8 * (cur & 3))) & 0xffu;
                bnd[l] = (unsigned char)cur;
            }
        }
        __syncthreads();

        // ---- Phase C: expand within chunk, write tags
        float* otag = out_tags + b * (3 * TT) + h * TT;
        unsigned curr = (lane == 63) ? (unsigned)last_ : (unsigned)bnd[lane + 1];
#pragma unroll
        for (int j = 7; j >= 0; --j) {
            unsigned d = (curr < 4) ? rw[2 * j] : rw[2 * j + 1];
            curr = (d >> (8 * (curr & 3))) & 0xffu;
            otag[t0 + j] = (float)((int)curr + off);
        }
    }
}

// ---------------------------------------------------------------------------
// Kernel 3: deterministic loss reduction (192 partials -> scalar)
// ---------------------------------------------------------------------------
__global__ __launch_bounds__(64) void loss_reduce(
    const float* __restrict__ partial, float* __restrict__ out_loss)
{
    int lane = threadIdx.x;
    float s = partial[lane] + partial[lane + 64] + partial[lane + 128];
#pragma unroll
    for (int d = 1; d <= 32; d <<= 1) s += __shfl_xor(s, d);
    if (lane == 0) *out_loss = s;
}

// ---------------------------------------------------------------------------
extern "C" void kernel_launch(void* const* d_in, const int* in_sizes, int n_in,
                              void* d_out, int out_size, void* d_ws, size_t ws_size,
                              hipStream_t stream) {
    const float* enc    = (const float*)d_in[0];
    const int*   labels = (const int*)d_in[1];
    const int*   lens   = (const int*)d_in[2];
    const float* Wt     = (const float*)d_in[3];
    const float* bt     = (const float*)d_in[4];
    const float* Wp     = (const float*)d_in[5];
    const float* bpv    = (const float*)d_in[6];
    const float* Wm     = (const float*)d_in[7];
    const float* bm     = (const float*)d_in[8];
    const float* tr_t   = (const float*)d_in[9];
    const float* tr_p   = (const float*)d_in[10];
    const float* tr_m   = (const float*)d_in[11];

    float* out = (float*)d_out;
    float* partial = (float*)d_ws;   // 192 floats

    gemm_heads<<<ROWS / 64, 256, 0, stream>>>(enc, Wt, bt, Wp, bpv, Wm, bm, out);
    crf_vit<<<192, 64, 0, stream>>>(out, labels, lens, tr_t, tr_p, tr_m,
                                    out + TAGS_OFF, partial);
    loss_reduce<<<1, 64, 0, stream>>>(partial, out + LOSS_OFF);
}

// Round 4
// 150.571 us; speedup vs baseline: 4.2328x; 1.0888x over previous
//
#include <hip/hip_runtime.h>
#include <hip/hip_bf16.h>
#include <math.h>

#define BATCH 64
#define TT 512
#define HH 1024
#define KK 8
#define ROWS (BATCH * TT)          // 32768
#define SEG  (ROWS * KK)           // 262144 floats per logits output
#define TAGS_OFF (3 * SEG)         // 786432
#define LOSS_OFF (TAGS_OFF + BATCH * 3 * TT)  // 884736

#define FMA8(base, w0, w1, xe)                          \
    acc[base + 0] = fmaf(xe, w0.x, acc[base + 0]);      \
    acc[base + 1] = fmaf(xe, w0.y, acc[base + 1]);      \
    acc[base + 2] = fmaf(xe, w0.z, acc[base + 2]);      \
    acc[base + 3] = fmaf(xe, w0.w, acc[base + 3]);      \
    acc[base + 4] = fmaf(xe, w1.x, acc[base + 4]);      \
    acc[base + 5] = fmaf(xe, w1.y, acc[base + 5]);      \
    acc[base + 6] = fmaf(xe, w1.z, acc[base + 6]);      \
    acc[base + 7] = fmaf(xe, w1.w, acc[base + 7]);

// ---------------------------------------------------------------------------
// Kernel 1: fused 3-head GEMM (unchanged from R3: 512 blocks x 4 waves,
// per-wave private double-buffered pipeline, transposed LDS x-tiles).
// ---------------------------------------------------------------------------
__global__ __launch_bounds__(256, 2) void gemm_heads(
    const float* __restrict__ enc,
    const float* __restrict__ Wt, const float* __restrict__ bt,
    const float* __restrict__ Wp, const float* __restrict__ bpv,
    const float* __restrict__ Wm, const float* __restrict__ bm,
    float* __restrict__ out)
{
    __shared__ float xl[4][2][16][65];
    __shared__ float red[3][64][25];

    int tid  = threadIdx.x;
    int lane = tid & 63;
    int wv   = __builtin_amdgcn_readfirstlane(tid >> 6);
    int rowbase = blockIdx.x * 64;
    const float* encb = enc + (size_t)rowbase * HH + wv * 256;

    int srow = lane >> 2;
    int sslot = lane & 3;

    float acc[24];
#pragma unroll
    for (int c = 0; c < 24; ++c) acc[c] = 0.f;

    float4 sreg[4];

#define LOADT(it)                                                             \
    {                                                                         \
        _Pragma("unroll")                                                     \
        for (int j = 0; j < 4; ++j)                                           \
            sreg[j] = *(const float4*)(encb + (size_t)(srow + 16 * j) * HH +  \
                                       (it) * 16 + sslot * 4);                \
    }
#define WRITET(buf)                                                           \
    {                                                                         \
        _Pragma("unroll")                                                     \
        for (int j = 0; j < 4; ++j) {                                         \
            xl[wv][buf][sslot * 4 + 0][srow + 16 * j] = sreg[j].x;            \
            xl[wv][buf][sslot * 4 + 1][srow + 16 * j] = sreg[j].y;            \
            xl[wv][buf][sslot * 4 + 2][srow + 16 * j] = sreg[j].z;            \
            xl[wv][buf][sslot * 4 + 3][srow + 16 * j] = sreg[j].w;            \
        }                                                                     \
    }

    LOADT(0);
    WRITET(0);

    for (int it = 0; it < 16; ++it) {
        int cb = it & 1;
        if (it < 15) LOADT(it + 1);

        const float* Wqt = Wt + (size_t)(wv * 256 + it * 16) * 8;
        const float* Wqp = Wp + (size_t)(wv * 256 + it * 16) * 8;
        const float* Wqm = Wm + (size_t)(wv * 256 + it * 16) * 8;

#pragma unroll 4
        for (int h = 0; h < 16; ++h) {
            float4 t0 = ((const float4*)(Wqt + h * 8))[0];
            float4 t1 = ((const float4*)(Wqt + h * 8))[1];
            float4 p0 = ((const float4*)(Wqp + h * 8))[0];
            float4 p1 = ((const float4*)(Wqp + h * 8))[1];
            float4 m0 = ((const float4*)(Wqm + h * 8))[0];
            float4 m1 = ((const float4*)(Wqm + h * 8))[1];
            float x = xl[wv][cb][h][lane];
            FMA8(0, t0, t1, x);
            FMA8(8, p0, p1, x);
            FMA8(16, m0, m1, x);
        }
        if (it < 15) WRITET(cb ^ 1);
    }
#undef LOADT
#undef WRITET

    if (wv != 0) {
#pragma unroll
        for (int c = 0; c < 24; ++c) red[wv - 1][lane][c] = acc[c];
    }
    __syncthreads();
    if (wv == 0) {
        float s[24];
#pragma unroll
        for (int c = 0; c < 24; ++c)
            s[c] = acc[c] + red[0][lane][c] + red[1][lane][c] + red[2][lane][c];
        size_t row = rowbase + lane;
        float* o0 = out + row * 8;
        float* o1 = out + SEG + row * 8;
        float* o2 = out + 2 * (size_t)SEG + row * 8;
        ((float4*)o0)[0] = make_float4(s[0] + bt[0],  s[1] + bt[1],  s[2] + bt[2],  s[3] + bt[3]);
        ((float4*)o0)[1] = make_float4(s[4] + bt[4],  s[5] + bt[5],  s[6] + bt[6],  s[7] + bt[7]);
        ((float4*)o1)[0] = make_float4(s[8] + bpv[0], s[9] + bpv[1], s[10] + bpv[2], s[11] + bpv[3]);
        ((float4*)o1)[1] = make_float4(s[12] + bpv[4], s[13] + bpv[5], s[14] + bpv[6], s[15] + bpv[7]);
        ((float4*)o2)[0] = make_float4(s[16] + bm[0], s[17] + bm[1], s[18] + bm[2], s[19] + bm[3]);
        ((float4*)o2)[1] = make_float4(s[20] + bm[4], s[21] + bm[5], s[22] + bm[6], s[23] + bm[7]);
    }
}

// ---------------------------------------------------------------------------
// Pure-VALU cross-lane helpers (no DS on the recurrence chain):
//   xor1 = quad_perm 0xB1, xor2 = quad_perm 0x4E, xor7 = row_half_mirror 0x141
//   ({1,2,7} spans [0,8) -> full 8-group reduce), xor8 = row_ror:8 (0x128),
//   xor16/xor32 = v_permlane16/32_swap_b32 + cndmask (gfx950), DS fallback.
// ---------------------------------------------------------------------------
#define DPPF(x, ctrl) __int_as_float(__builtin_amdgcn_update_dpp(              \
    0, __float_as_int(x), ctrl, 0xF, 0xF, true))
#define SWIZF(x, pat) __int_as_float(__builtin_amdgcn_ds_swizzle(              \
    __float_as_int(x), pat))
#define BPERMF(a, x)  __int_as_float(__builtin_amdgcn_ds_bpermute(             \
    a, __float_as_int(x)))

#if __has_builtin(__builtin_amdgcn_permlane16_swap)
__device__ __forceinline__ float xor16f(float x, int lane) {
    typedef unsigned uv2 __attribute__((ext_vector_type(2)));
    uv2 r = __builtin_amdgcn_permlane16_swap(__float_as_uint(x), __float_as_uint(x), false, false);
    return __uint_as_float((lane & 16) ? r.x : r.y);
}
#else
__device__ __forceinline__ float xor16f(float x, int lane) { return SWIZF(x, 0x401F); }
#endif

#if __has_builtin(__builtin_amdgcn_permlane32_swap)
__device__ __forceinline__ float xor32f(float x, int lane) {
    typedef unsigned uv2 __attribute__((ext_vector_type(2)));
    uv2 r = __builtin_amdgcn_permlane32_swap(__float_as_uint(x), __float_as_uint(x), false, false);
    return __uint_as_float((lane & 32) ? r.x : r.y);
}
#else
__device__ __forceinline__ float xor32f(float x, int lane) {
    return BPERMF(((lane ^ 32) << 2), x);
}
#endif

__global__ __launch_bounds__(64) void crf_vit(
    const float* __restrict__ logits,
    const int* __restrict__ labels,
    const int* __restrict__ lens,
    const float* __restrict__ trans_t,
    const float* __restrict__ trans_p,
    const float* __restrict__ trans_m,
    float* __restrict__ out_tags,
    float* __restrict__ partial)
{
    __shared__ float llds[TT * KK];        // 16 KB
    __shared__ unsigned bpw[TT * 2];       // 4 KB backpointers
    __shared__ unsigned fmapw[64][2];
    __shared__ unsigned char bnd[64];

    int blk = blockIdx.x;
    int h   = blk >> 6;
    int b   = blk & 63;
    int lane = threadIdx.x;
    int hi = lane >> 3, lo = lane & 7;
    unsigned char* bpb = (unsigned char*)bpw;

    const float* L = logits + ((size_t)h * BATCH + b) * (TT * KK);
    const float4* Lv = (const float4*)L;
    float4* lv = (float4*)llds;
#pragma unroll
    for (int i = 0; i < 16; ++i) lv[lane + 64 * i] = Lv[lane + 64 * i];
    __syncthreads();

    const float* TR = (h == 0) ? trans_t : (h == 1) ? trans_p : trans_m;
    float trA = TR[lo * 8 + hi];   // even step: kp=lo, kn=hi
    float trB = TR[hi * 8 + lo];   // odd step:  kp=hi, kn=lo
    int len = lens[b];

    float av = llds[lo];
    float al = av;

    float m0 = __int_as_float(__builtin_amdgcn_readfirstlane(__float_as_int(al)));
    float m_use = m0, m1 = m0, m2 = m0, m3 = m0;

    // even step: reduce over lo field via DPP xor1, xor2, xor7
#define VSTEP_EVEN(t, LT)                                                      \
    {                                                                          \
        float v0 = av + trA;                                                   \
        float ra = fmaxf(v0, DPPF(v0, 0xB1));                                  \
        float rb = fmaxf(ra, DPPF(ra, 0x4E));                                  \
        float vmax = fmaxf(rb, DPPF(rb, 0x141));                               \
        unsigned long long mk = __ballot(v0 == vmax);                          \
        int vi = __builtin_ctz(((unsigned)(mk >> (lane & 56))) & 0xffu);       \
        if (lo == 0) bpb[(t) * 8 + hi] = (unsigned char)vi;                    \
        av = vmax + (LT);                                                      \
        float e0 = __expf(al + trA - m_use);                                   \
        float sa = e0 + DPPF(e0, 0xB1);                                        \
        float sb = sa + DPPF(sa, 0x4E);                                        \
        float es = sb + DPPF(sb, 0x141);                                       \
        float nal = m_use + __logf(es) + (LT);                                 \
        if ((t) < len) al = nal;                                               \
        m_use = m1; m1 = m2; m2 = m3;                                          \
        m3 = __int_as_float(__builtin_amdgcn_readfirstlane(__float_as_int(al)));\
    }
    // odd step: reduce over hi field via DPP ror:8, permlane16, permlane32
#define VSTEP_ODD(t, LT)                                                       \
    {                                                                          \
        float v0 = av + trB;                                                   \
        float ra = fmaxf(v0, DPPF(v0, 0x128));                                 \
        float rb = fmaxf(ra, xor16f(ra, lane));                                \
        float vmax = fmaxf(rb, xor32f(rb, lane));                              \
        unsigned long long mk = __ballot(v0 == vmax);                          \
        unsigned long long sel = (mk >> lo) & 0x0101010101010101ULL;           \
        int vi = __builtin_ctzll(sel) >> 3;                                    \
        if (hi == 0) bpb[(t) * 8 + lo] = (unsigned char)vi;                    \
        av = vmax + (LT);                                                      \
        float e0 = __expf(al + trB - m_use);                                   \
        float sa = e0 + DPPF(e0, 0x128);                                       \
        float sb = sa + xor16f(sa, lane);                                      \
        float es = sb + xor32f(sb, lane);                                      \
        float nal = m_use + __logf(es) + (LT);                                 \
        if ((t) < len) al = nal;                                               \
        m_use = m1; m1 = m2; m2 = m3;                                          \
        m3 = __int_as_float(__builtin_amdgcn_readfirstlane(__float_as_int(al)));\
    }

    float ltA = llds[8 + hi];
    float ltB = llds[16 + lo];
    for (int t = 1; t <= 509; t += 2) {
        float ltA2 = llds[(t + 2) * 8 + hi];            // prefetch
        int tb = (t + 3 <= 511) ? (t + 3) : 511;
        float ltB2 = llds[tb * 8 + lo];
        VSTEP_EVEN(t, ltA);
        VSTEP_ODD(t + 1, ltB);
        ltA = ltA2; ltB = ltB2;
    }
    VSTEP_EVEN(511, ltA);
#undef VSTEP_EVEN
#undef VSTEP_ODD

    {
        // ---- last = argmax of final viterbi alpha (indexed by hi, replicated over lo)
        float ra = fmaxf(av, DPPF(av, 0x128));
        float rb = fmaxf(ra, xor16f(ra, lane));
        float vmax = fmaxf(rb, xor32f(rb, lane));
        unsigned long long mk = __ballot(av == vmax);
        int last_ = __builtin_ctzll(mk) >> 3;

        // ---- logZ: reduce over hi field (al indexed by hi, replicated over lo)
        float za = fmaxf(al, DPPF(al, 0x128));
        float zb = fmaxf(za, xor16f(za, lane));
        float zmax = fmaxf(zb, xor32f(zb, lane));
        float ze0 = __expf(al - zmax);
        float zs = ze0 + DPPF(ze0, 0x128);
        float zs2 = zs + xor16f(zs, lane);
        float zsum = zs2 + xor32f(zs2, lane);
        float logZ = zmax + __logf(zsum);

        // ---- emit + transition scores (lane-parallel over t)
        const int* lab = labels + b * (3 * TT) + h * TT;
        int off = h * 8;
        float sc = 0.f;
#pragma unroll
        for (int j = 0; j < 8; ++j) {
            int t = lane + 64 * j;
            if (t < len) {
                int tg = lab[t] - off;
                sc += llds[t * 8 + tg];
                if (t >= 1) {
                    int tp = lab[t - 1] - off;
                    sc += TR[tp * 8 + tg];
                }
            }
        }
#pragma unroll
        for (int d = 1; d <= 32; d <<= 1) sc += __shfl_xor(sc, d);

        if (lane == 0) partial[blk] = logZ - sc;

        __syncthreads();  // bp writes visible

        // ---- Phase A: lane l composes bp maps for t in [8l+1, 8l+8]
        int t0 = lane * 8;
        unsigned rw[16];
#pragma unroll
        for (int j = 0; j < 8; ++j) {
            int t = t0 + 1 + j;
            if (t <= 511) { rw[2 * j] = bpw[t * 2]; rw[2 * j + 1] = bpw[t * 2 + 1]; }
            else          { rw[2 * j] = 0x03020100u; rw[2 * j + 1] = 0x07060504u; }
        }
        unsigned sv[8];
#pragma unroll
        for (int i = 0; i < 8; ++i) sv[i] = i;
#pragma unroll
        for (int j = 7; j >= 0; --j) {
            unsigned d0 = rw[2 * j], d1 = rw[2 * j + 1];
#pragma unroll
            for (int i = 0; i < 8; ++i) {
                unsigned s = sv[i];
                unsigned d = (s < 4) ? d0 : d1;
                sv[i] = (d >> (8 * (s & 3))) & 0xffu;
            }
        }
        fmapw[lane][0] = sv[0] | (sv[1] << 8) | (sv[2] << 16) | (sv[3] << 24);
        fmapw[lane][1] = sv[4] | (sv[5] << 8) | (sv[6] << 16) | (sv[7] << 24);
        __syncthreads();

        // ---- Phase B: lane 0 walks 64 chunk maps
        if (lane == 0) {
            unsigned cur = (unsigned)last_;
            for (int l = 63; l >= 0; --l) {
                unsigned d = (cur < 4) ? fmapw[l][0] : fmapw[l][1];
                cur = (d >> (8 * (cur & 3))) & 0xffu;
                bnd[l] = (unsigned char)cur;
            }
        }
        __syncthreads();

        // ---- Phase C: expand within chunk, write tags
        float* otag = out_tags + b * (3 * TT) + h * TT;
        unsigned curr = (lane == 63) ? (unsigned)last_ : (unsigned)bnd[lane + 1];
#pragma unroll
        for (int j = 7; j >= 0; --j) {
            unsigned d = (curr < 4) ? rw[2 * j] : rw[2 * j + 1];
            curr = (d >> (8 * (curr & 3))) & 0xffu;
            otag[t0 + j] = (float)((int)curr + off);
        }
    }
}

// ---------------------------------------------------------------------------
// Kernel 3: deterministic loss reduction (192 partials -> scalar)
// ---------------------------------------------------------------------------
__global__ __launch_bounds__(64) void loss_reduce(
    const float* __restrict__ partial, float* __restrict__ out_loss)
{
    int lane = threadIdx.x;
    float s = partial[lane] + partial[lane + 64] + partial[lane + 128];
#pragma unroll
    for (int d = 1; d <= 32; d <<= 1) s += __shfl_xor(s, d);
    if (lane == 0) *out_loss = s;
}

// ---------------------------------------------------------------------------
extern "C" void kernel_launch(void* const* d_in, const int* in_sizes, int n_in,
                              void* d_out, int out_size, void* d_ws, size_t ws_size,
                              hipStream_t stream) {
    const float* enc    = (const float*)d_in[0];
    const int*   labels = (const int*)d_in[1];
    const int*   lens   = (const int*)d_in[2];
    const float* Wt     = (const float*)d_in[3];
    const float* bt     = (const float*)d_in[4];
    const float* Wp     = (const float*)d_in[5];
    const float* bpv    = (const float*)d_in[6];
    const float* Wm     = (const float*)d_in[7];
    const float* bm     = (const float*)d_in[8];
    const float* tr_t   = (const float*)d_in[9];
    const float* tr_p   = (const float*)d_in[10];
    const float* tr_m   = (const float*)d_in[11];

    float* out = (float*)d_out;
    float* partial = (float*)d_ws;   // 192 floats

    gemm_heads<<<ROWS / 64, 256, 0, stream>>>(enc, Wt, bt, Wp, bpv, Wm, bm, out);
    crf_vit<<<192, 64, 0, stream>>>(out, labels, lens, tr_t, tr_p, tr_m,
                                    out + TAGS_OFF, partial);
    loss_reduce<<<1, 64, 0, stream>>>(partial, out + LOSS_OFF);
}